// Round 6
// baseline (3328.825 us; speedup 1.0000x reference)
//
#include <hip/hip_runtime.h>
#include <math.h>

typedef __bf16 bf16_t;
typedef __bf16 bf16x4 __attribute__((ext_vector_type(4)));
typedef __bf16 bf16x8 __attribute__((ext_vector_type(8)));
typedef float f32x4 __attribute__((ext_vector_type(4)));
typedef unsigned long long u64;

#define MFMA_16x16x32(A, B, C) __builtin_amdgcn_mfma_f32_16x16x32_bf16((A), (B), (C), 0, 0, 0)

static constexpr int Bn = 64;    // batch
static constexpr int Tn = 512;   // time
static constexpr int Dn = 1024;  // input dim
static constexpr int Hn = 2048;  // hidden
static constexpr int Cn = 5;     // classes
static constexpr int NGB = 128;  // blocks per batch-group
static constexpr int NGRP = 2;   // batch groups (32 rows each)
static constexpr int NBT = NGB * NGRP;  // 256 blocks = full GPU
static constexpr int NW = 16;    // waves per block (1024 threads)

// LDS swizzle for the xw GEMM tiles (32 bf16 = 64B rows)
#define SWZ64(row, kb)  ((((row) * 64) + (kb)) ^ (((row) & 3) << 4))

// ---------------- conversion kernels ----------------
__global__ __launch_bounds__(256) void cvt_bf16_k(const float* __restrict__ in,
                                                  bf16_t* __restrict__ out, int n4) {
  int i = blockIdx.x * 256 + threadIdx.x;
  if (i >= n4) return;
  float4 v = reinterpret_cast<const float4*>(in)[i];
  bf16x4 o;
  o[0] = (bf16_t)v.x; o[1] = (bf16_t)v.y; o[2] = (bf16_t)v.z; o[3] = (bf16_t)v.w;
  reinterpret_cast<bf16x4*>(out)[i] = o;
}

__global__ __launch_bounds__(256) void cvt_hilo_k(const float* __restrict__ in,
                                                  bf16_t* __restrict__ hi,
                                                  bf16_t* __restrict__ lo, int n4) {
  int i = blockIdx.x * 256 + threadIdx.x;
  if (i >= n4) return;
  float4 v = reinterpret_cast<const float4*>(in)[i];
  float f[4] = {v.x, v.y, v.z, v.w};
  bf16x4 h, l;
#pragma unroll
  for (int j = 0; j < 4; ++j) {
    bf16_t hb = (bf16_t)f[j];
    h[j] = hb;
    l[j] = (bf16_t)(f[j] - (float)hb);
  }
  reinterpret_cast<bf16x4*>(hi)[i] = h;
  reinterpret_cast<bf16x4*>(lo)[i] = l;
}

// ---------------- xw projection GEMM ----------------
__global__ __launch_bounds__(256) void gemm_xw_k(const float* __restrict__ A,
                                                 const bf16_t* __restrict__ Bw,
                                                 const float* __restrict__ bias,
                                                 bf16_t* __restrict__ C) {
  constexpr int K = Dn;
  constexpr int N = Hn;
  constexpr int NT = K / 32;
  __shared__ char As[2][128 * 64];
  __shared__ char Bs[2][128 * 64];

  const int tid = threadIdx.x;
  const int lane = tid & 63;
  const int wv = tid >> 6;
  const int wm = (wv >> 1) * 64;
  const int wn = (wv & 1) * 64;
  const int cl = lane & 15;
  const int kh = lane >> 4;
  const long m0 = (long)blockIdx.y * 128;
  const long n0 = (long)blockIdx.x * 128;

  const int srow = tid >> 1;
  const int scolb = (tid & 1) * 32;

  f32x4 acc[4][4] = {};
  float4 pa[4];
  uint4 pb[2];

  auto issue = [&](int kt) {
    const float* ap = A + (m0 + srow) * K + kt * 32 + (tid & 1) * 16;
#pragma unroll
    for (int i = 0; i < 4; ++i) pa[i] = reinterpret_cast<const float4*>(ap)[i];
    const bf16_t* bp = Bw + (n0 + srow) * K + kt * 32 + (tid & 1) * 16;
    pb[0] = reinterpret_cast<const uint4*>(bp)[0];
    pb[1] = reinterpret_cast<const uint4*>(bp)[1];
  };
  auto commit = [&](int buf) {
    bf16x8 a0, a1;
    a0[0] = (bf16_t)pa[0].x; a0[1] = (bf16_t)pa[0].y; a0[2] = (bf16_t)pa[0].z; a0[3] = (bf16_t)pa[0].w;
    a0[4] = (bf16_t)pa[1].x; a0[5] = (bf16_t)pa[1].y; a0[6] = (bf16_t)pa[1].z; a0[7] = (bf16_t)pa[1].w;
    a1[0] = (bf16_t)pa[2].x; a1[1] = (bf16_t)pa[2].y; a1[2] = (bf16_t)pa[2].z; a1[3] = (bf16_t)pa[2].w;
    a1[4] = (bf16_t)pa[3].x; a1[5] = (bf16_t)pa[3].y; a1[6] = (bf16_t)pa[3].z; a1[7] = (bf16_t)pa[3].w;
    *reinterpret_cast<bf16x8*>(&As[buf][SWZ64(srow, scolb)]) = a0;
    *reinterpret_cast<bf16x8*>(&As[buf][SWZ64(srow, scolb + 16)]) = a1;
    *reinterpret_cast<uint4*>(&Bs[buf][SWZ64(srow, scolb)]) = pb[0];
    *reinterpret_cast<uint4*>(&Bs[buf][SWZ64(srow, scolb + 16)]) = pb[1];
  };

  issue(0);
  commit(0);
  for (int kt = 0; kt < NT; ++kt) {
    const int buf = kt & 1;
    __syncthreads();
    if (kt + 1 < NT) issue(kt + 1);
    bf16x8 af[4], bfr[4];
#pragma unroll
    for (int i = 0; i < 4; ++i)
      af[i] = *reinterpret_cast<const bf16x8*>(&As[buf][SWZ64(wm + i * 16 + cl, kh * 16)]);
#pragma unroll
    for (int j = 0; j < 4; ++j)
      bfr[j] = *reinterpret_cast<const bf16x8*>(&Bs[buf][SWZ64(wn + j * 16 + cl, kh * 16)]);
#pragma unroll
    for (int i = 0; i < 4; ++i)
#pragma unroll
      for (int j = 0; j < 4; ++j)
        acc[i][j] = MFMA_16x16x32(af[i], bfr[j], acc[i][j]);
    if (kt + 1 < NT) commit((kt + 1) & 1);
  }

  const int rl4 = kh * 4;
#pragma unroll
  for (int j = 0; j < 4; ++j) {
    const long gcol = n0 + wn + j * 16 + cl;
    const float bv = bias[gcol];
#pragma unroll
    for (int i = 0; i < 4; ++i) {
      const long grow = m0 + wm + i * 16 + rl4;
#pragma unroll
      for (int q = 0; q < 4; ++q)
        C[(grow + q) * N + gcol] = (bf16_t)(acc[i][j][q] + bv);
    }
  }
}

// ---------------- persistent scan kernel ----------------
// Round-6 structure: 256 blocks x 1024 THREADS (16 waves), 1 block/CU,
// 4 waves/SIMD. 2 batch-groups x 128 blocks, group-local barriers (r4).
// Within a block: 16 output cols, 16 waves = 2 row-tiles x 8 k-splits.
// Each wave reads 16 rows x 256 k of h (8KB serial stream: HALF of r5);
// 8 k-split partials reduce through 16KB LDS scratch; the storer's combine
// reads are VECTORIZED float4 (conflict-free 1KB contiguous per wave) --
// r5's 16 scalar reads were 8-way bank conflicted.
// Coherence (r3, kept): h stores sc0sc1 -> MALL, acked before flag;
// h loads plain cached on virgin rotated slots (no fence). Fallback rot=0:
// ping-pong + per-step acquire fence.
__global__ __launch_bounds__(1024, 1) void scan_k(
    const bf16_t* __restrict__ Uhi, const bf16_t* __restrict__ Ulo,
    const float* __restrict__ Ub, const bf16_t* __restrict__ XW,
    bf16_t* __restrict__ Hc, long Hstep, int rot,
    const bf16_t* __restrict__ V1w, const float* __restrict__ V1b,
    float* __restrict__ Z1,
    const float* __restrict__ V2w, const float* __restrict__ V2b,
    float* __restrict__ out, unsigned* __restrict__ slots) {
  extern __shared__ char smem[];
  char* Uh_s = smem;                        // 64 KB
  char* Ul_s = smem + 65536;                // 64 KB
  float* red = (float*)(smem + 131072);     // 16 KB k-split partial scratch [16][256]

  const int tid = threadIdx.x;
  const int lane = tid & 63;
  const int wv = tid >> 6;             // 0..15
  const int cl = lane & 15;
  const int kh = lane >> 4;
  const int bid = blockIdx.x;
  const int g = bid >> 7;              // batch group (0/1)
  const int j = bid & (NGB - 1);       // group-local block id
  const int n0 = j * 16;               // owned columns
  const int r = wv >> 3;               // row-tile (0/1) within group slice
  const int ks = wv & 7;               // k-split (0..7), 256 cols each
  const int row0 = 32 * g + 16 * r;    // global batch row base for this wave
  unsigned* gslots = slots + (size_t)g * NGB * 32;

  // ---- stage U slice into LDS (once; 1024 threads: 64 segs x 16 cols) ----
  {
    const int col = tid >> 6;          // 0..15
    const int seg = tid & 63;          // 0..63
    const char* srch = reinterpret_cast<const char*>(Uhi + (long)(n0 + col) * Hn);
    const char* srcl = reinterpret_cast<const char*>(Ulo + (long)(n0 + col) * Hn);
#pragma unroll
    for (int c = 0; c < 4; ++c) {
      const int byteoff = seg * 16 + c * 1024;
      uint4 vh = *reinterpret_cast<const uint4*>(srch + byteoff);
      uint4 vl = *reinterpret_cast<const uint4*>(srcl + byteoff);
      const int sw = col * 4096 + (byteoff ^ ((col & 7) << 4));
      *reinterpret_cast<uint4*>(Uh_s + sw) = vh;
      *reinterpret_cast<uint4*>(Ul_s + sw) = vl;
    }
  }
  __syncthreads();

  const int lds_base = cl * 4096;
  const int lds_x = (cl & 7) << 4;
  const int kbase = ks * 512;          // byte offset of this wave's k-split
  // store-side mapping (waves ks==0 only): one coalesced u64 per lane
  const int st_row = lane >> 2;        // 0..15
  const int st_cg = lane & 3;          // col group *4
  const bool storer = (ks == 0);

  float4 bv4 = {0.f, 0.f, 0.f, 0.f};
  if (storer) bv4 = *reinterpret_cast<const float4*>(Ub + n0 + st_cg * 4);
  const long xw_off = (long)(row0 + st_row) * (Tn * Hn) + n0 + st_cg * 4;

  // prefetch xw add-path for t=0 (storing lanes)
  bf16x4 ad = {};
  if (storer) ad = *reinterpret_cast<const bf16x4*>(XW + xw_off);

  // h slot pointers: t reads hin, writes hout.
  bf16_t* hin = Hc;            // slot 0 = zeros
  bf16_t* hout = Hc + Hstep;   // slot 1

  for (int t = 0; t < Tn; ++t) {
    const bf16_t* arow = hin + (long)(row0 + cl) * Hn + ks * 256 + kh * 8;

    // preload ALL h fragments for this wave's k-split (8 outstanding loads)
    bf16x8 av0[4], av1[4];
#pragma unroll
    for (int it = 0; it < 4; ++it) {
      av0[it] = *reinterpret_cast<const bf16x8*>(arow + it * 64);
      av1[it] = *reinterpret_cast<const bf16x8*>(arow + it * 64 + 32);
    }

    f32x4 ah0 = {}, ah1 = {}, al0 = {}, al1 = {};
#pragma unroll
    for (int it = 0; it < 4; ++it) {
      const int kb0 = kbase + it * 128 + kh * 16;
      const int kb1 = kb0 + 64;
      bf16x8 bh0 = *reinterpret_cast<const bf16x8*>(Uh_s + lds_base + (kb0 ^ lds_x));
      bf16x8 bl0 = *reinterpret_cast<const bf16x8*>(Ul_s + lds_base + (kb0 ^ lds_x));
      bf16x8 bh1 = *reinterpret_cast<const bf16x8*>(Uh_s + lds_base + (kb1 ^ lds_x));
      bf16x8 bl1 = *reinterpret_cast<const bf16x8*>(Ul_s + lds_base + (kb1 ^ lds_x));
      ah0 = MFMA_16x16x32(av0[it], bh0, ah0);
      al0 = MFMA_16x16x32(av0[it], bl0, al0);
      ah1 = MFMA_16x16x32(av1[it], bh1, ah1);
      al1 = MFMA_16x16x32(av1[it], bl1, al1);
    }

    // k-split partials -> LDS
#pragma unroll
    for (int q = 0; q < 4; ++q)
      red[wv * 256 + (kh * 4 + q) * 16 + cl] = ah0[q] + ah1[q] + al0[q] + al1[q];
    __syncthreads();

    // waves ks==0: combine 8 k-splits (float4, conflict-free), bias+xw+relu,
    // one coalesced sc0sc1 store
    if (storer) {
      const int ri = st_row * 16 + st_cg * 4;  // float4-aligned base
      float4 s = {0.f, 0.f, 0.f, 0.f};
#pragma unroll
      for (int w = 0; w < 8; ++w) {
        float4 p = *reinterpret_cast<const float4*>(&red[(wv + w) * 256 + ri]);
        s.x += p.x; s.y += p.y; s.z += p.z; s.w += p.w;
      }
      bf16x4 hv;
      hv[0] = (bf16_t)fmaxf(s.x + bv4.x + (float)ad[0], 0.f);
      hv[1] = (bf16_t)fmaxf(s.y + bv4.y + (float)ad[1], 0.f);
      hv[2] = (bf16_t)fmaxf(s.z + bv4.z + (float)ad[2], 0.f);
      hv[3] = (bf16_t)fmaxf(s.w + bv4.w + (float)ad[3], 0.f);
      __hip_atomic_store(
          reinterpret_cast<u64*>(hout + (long)(row0 + st_row) * Hn + n0 + st_cg * 4),
          *reinterpret_cast<const u64*>(&hv), __ATOMIC_RELAXED,
          __HIP_MEMORY_SCOPE_AGENT);
    }

    // ---- group-local broadcast barrier ----
    const unsigned tgt = (unsigned)(t + 1);
    __syncthreads();  // drains vmcnt(0): all sc1 h-stores acked at coherence point
    asm volatile("" ::: "memory");
    if (tid == 0)
      __hip_atomic_store(gslots + (size_t)j * 32, tgt,
                         __ATOMIC_RELAXED, __HIP_MEMORY_SCOPE_AGENT);

    // prefetch XW for t+1 — hides under the poll
    bf16x4 adn = {};
    if (storer && (t + 1 < Tn))
      adn = *reinterpret_cast<const bf16x4*>(XW + xw_off + (long)(t + 1) * Hn);

    if (tid < 64) {  // wave 0 polls this group's 128 slots
      for (;;) {
        unsigned a = __hip_atomic_load(gslots + (size_t)tid * 32,
                                       __ATOMIC_RELAXED, __HIP_MEMORY_SCOPE_AGENT);
        unsigned b = __hip_atomic_load(gslots + (size_t)(tid + 64) * 32,
                                       __ATOMIC_RELAXED, __HIP_MEMORY_SCOPE_AGENT);
        if (__all((a >= tgt) && (b >= tgt))) break;
      }
      // rotation: no fence needed (virgin addresses can't be stale).
      if (!rot) __builtin_amdgcn_fence(__ATOMIC_ACQUIRE, "agent");
    }
    asm volatile("" ::: "memory");
    __syncthreads();

    ad = adn;

    // advance slots
    bf16_t* nn = hout;
    hout = rot ? (hout + Hstep) : hin;
    hin = nn;
  }

  // ---- V1 layer: z1 = relu(h_last @ V1^T + b1) for this group's 32 rows ----
  {
    const bf16_t* arow = hin + (long)(row0 + cl) * Hn + ks * 256 + kh * 8;
    const bf16_t* vrow = V1w + (long)(n0 + cl) * Hn + ks * 256 + kh * 8;
    f32x4 z0 = {}, z1a = {};
#pragma unroll
    for (int it = 0; it < 4; ++it) {
      bf16x8 a0 = *reinterpret_cast<const bf16x8*>(arow + it * 64);
      bf16x8 a1 = *reinterpret_cast<const bf16x8*>(arow + it * 64 + 32);
      bf16x8 b0 = *reinterpret_cast<const bf16x8*>(vrow + it * 64);
      bf16x8 b1 = *reinterpret_cast<const bf16x8*>(vrow + it * 64 + 32);
      z0 = MFMA_16x16x32(a0, b0, z0);
      z1a = MFMA_16x16x32(a1, b1, z1a);
    }
#pragma unroll
    for (int q = 0; q < 4; ++q)
      red[wv * 256 + (kh * 4 + q) * 16 + cl] = z0[q] + z1a[q];
    __syncthreads();
    if (storer) {
      const int ri = st_row * 16 + st_cg * 4;
      float4 s = {0.f, 0.f, 0.f, 0.f};
#pragma unroll
      for (int w = 0; w < 8; ++w) {
        float4 p = *reinterpret_cast<const float4*>(&red[(wv + w) * 256 + ri]);
        s.x += p.x; s.y += p.y; s.z += p.z; s.w += p.w;
      }
      float4 vb = *reinterpret_cast<const float4*>(V1b + n0 + st_cg * 4);
      float4 o;
      o.x = fmaxf(s.x + vb.x, 0.f);
      o.y = fmaxf(s.y + vb.y, 0.f);
      o.z = fmaxf(s.z + vb.z, 0.f);
      o.w = fmaxf(s.w + vb.w, 0.f);
      *reinterpret_cast<float4*>(Z1 + (long)(row0 + st_row) * Hn + n0 + st_cg * 4) = o;
    }
  }

  // ---- FULL-grid barrier before head reads Z1 (release + acquire, once) ----
  {
    const unsigned tgt = (unsigned)(Tn + 1);
    __syncthreads();
    if (tid == 0)
      __hip_atomic_store(slots + (size_t)bid * 32, tgt,
                         __ATOMIC_RELEASE, __HIP_MEMORY_SCOPE_AGENT);
    if (tid < 64) {
      for (;;) {
        unsigned a = __hip_atomic_load(slots + (size_t)tid * 32,
                                       __ATOMIC_RELAXED, __HIP_MEMORY_SCOPE_AGENT);
        unsigned b = __hip_atomic_load(slots + (size_t)(tid + 64) * 32,
                                       __ATOMIC_RELAXED, __HIP_MEMORY_SCOPE_AGENT);
        unsigned c = __hip_atomic_load(slots + (size_t)(tid + 128) * 32,
                                       __ATOMIC_RELAXED, __HIP_MEMORY_SCOPE_AGENT);
        unsigned d = __hip_atomic_load(slots + (size_t)(tid + 192) * 32,
                                       __ATOMIC_RELAXED, __HIP_MEMORY_SCOPE_AGENT);
        if (__all((a >= tgt) && (b >= tgt) && (c >= tgt) && (d >= tgt))) break;
      }
      __builtin_amdgcn_fence(__ATOMIC_ACQUIRE, "agent");
    }
    __syncthreads();
  }

  // ---- head: z2 = relu(z1 @ V2^T + b2); out = log_softmax ----
  if (bid < Bn) {
    const int b = bid;
    float p[Cn] = {0.f, 0.f, 0.f, 0.f, 0.f};
    for (int jj = tid; jj < Hn; jj += 1024) {
      const float x = Z1[(long)b * Hn + jj];
#pragma unroll
      for (int c = 0; c < Cn; ++c) p[c] += x * V2w[(long)c * Hn + jj];
    }
#pragma unroll
    for (int c = 0; c < Cn; ++c)
      for (int off = 32; off; off >>= 1) p[c] += __shfl_down(p[c], off, 64);

    float* redh = reinterpret_cast<float*>(smem);
    if (lane == 0) {
#pragma unroll
      for (int c = 0; c < Cn; ++c) redh[c * NW + wv] = p[c];
    }
    __syncthreads();
    if (tid == 0) {
      float z[Cn];
      float mx = 0.f;
#pragma unroll
      for (int c = 0; c < Cn; ++c) {
        float s16 = 0.f;
#pragma unroll
        for (int w = 0; w < NW; ++w) s16 += redh[c * NW + w];
        z[c] = fmaxf(s16 + V2b[c], 0.f);
        mx = fmaxf(mx, z[c]);
      }
      float s = 0.f;
#pragma unroll
      for (int c = 0; c < Cn; ++c) s += expf(z[c] - mx);
      const float ls = logf(s);
#pragma unroll
      for (int c = 0; c < Cn; ++c) out[b * Cn + c] = z[c] - mx - ls;
    }
  }
}

// ---------------- host ----------------
extern "C" void kernel_launch(void* const* d_in, const int* in_sizes, int n_in,
                              void* d_out, int out_size, void* d_ws, size_t ws_size,
                              hipStream_t stream) {
  const float* inputs = (const float*)d_in[0];
  const float* W_w = (const float*)d_in[1];
  const float* W_b = (const float*)d_in[2];
  const float* U_w = (const float*)d_in[3];
  const float* U_b = (const float*)d_in[4];
  const float* V1_w = (const float*)d_in[5];
  const float* V1_b = (const float*)d_in[6];
  const float* V2_w = (const float*)d_in[7];
  const float* V2_b = (const float*)d_in[8];
  float* out = (float*)d_out;

  size_t off = 0;
  auto alloc = [&](size_t bytes) {
    void* p = (char*)d_ws + off;
    off += (bytes + 255) & ~(size_t)255;
    return p;
  };
  bf16_t* Wbf = (bf16_t*)alloc((size_t)Hn * Dn * 2);
  bf16_t* Uhi = (bf16_t*)alloc((size_t)Hn * Hn * 2);
  bf16_t* Ulo = (bf16_t*)alloc((size_t)Hn * Hn * 2);
  bf16_t* V1bf = (bf16_t*)alloc((size_t)Hn * Hn * 2);
  bf16_t* XW = (bf16_t*)alloc((size_t)Bn * Tn * Hn * 2);
  float* Z1 = (float*)alloc((size_t)Bn * Hn * 4);
  unsigned* slots = (unsigned*)alloc((size_t)NBT * 32 * 4);  // 32 KB, 128B/slot

  // h chain: rotation if the workspace fits Tn+1 virgin slots, else ping-pong.
  const size_t slot_bytes = (size_t)Bn * Hn * 2;  // 256 KB
  const size_t rot_bytes = (size_t)(Tn + 1) * slot_bytes;
  const int rot = (ws_size - off) >= (rot_bytes + 256) ? 1 : 0;
  bf16_t* Hc = (bf16_t*)alloc(rot ? rot_bytes : 2 * slot_bytes);
  (void)ws_size;

  (void)hipFuncSetAttribute((const void*)scan_k,
                            hipFuncAttributeMaxDynamicSharedMemorySize, 147456);

  cvt_bf16_k<<<(Hn * Dn / 4 + 255) / 256, 256, 0, stream>>>(W_w, Wbf, Hn * Dn / 4);
  cvt_hilo_k<<<(Hn * Hn / 4 + 255) / 256, 256, 0, stream>>>(U_w, Uhi, Ulo, Hn * Hn / 4);
  cvt_bf16_k<<<(Hn * Hn / 4 + 255) / 256, 256, 0, stream>>>(V1_w, V1bf, Hn * Hn / 4);

  gemm_xw_k<<<dim3(Hn / 128, (Bn * Tn) / 128), 256, 0, stream>>>(inputs, Wbf, W_b, XW);

  (void)hipMemsetAsync(Hc, 0, slot_bytes, stream);  // slot 0 = h_0 = zeros
  (void)hipMemsetAsync(slots, 0, (size_t)NBT * 32 * 4, stream);

  scan_k<<<NBT, 1024, 147456, stream>>>(Uhi, Ulo, U_b, XW, Hc, (long)Bn * Hn, rot,
                                        V1bf, V1_b, Z1, V2_w, V2_b, out, slots);
}